// Round 11
// baseline (357.335 us; speedup 1.0000x reference)
//
#include <hip/hip_runtime.h>
#include <hip/hip_bf16.h>
#include <math.h>

#define N_NODES 3200
#define E_EDGES 50000
#define RBFN 16
#define HID 128
#define NS 32
#define NV 16
#define DD 80
#define WNUM 2304
#define CUTF 5.0f
#define EPSF 1e-8f

#define A1C 0.125f                  // 1/sqrt(2*NS)
#define A2C 0.17677669529663687f    // 1/sqrt(2*NV)
#define A3C 0.125f
#define A4C 0.17677669529663687f
#define A2ISQ 0.10206207261596575f  // A2C / sqrt(3)

typedef __attribute__((ext_vector_type(4))) float f32x4;
typedef __attribute__((ext_vector_type(8))) short bf16x8;

__device__ __forceinline__ float sigm(float x) { return 1.0f / (1.0f + __expf(-x)); }
__device__ __forceinline__ float silu_f(float x) { return x * sigm(x); }

__device__ __forceinline__ short bf16r(float x) {
    union { float f; unsigned u; } v; v.f = x;
    unsigned r = (v.u + 0x7fffu + ((v.u >> 16) & 1u)) >> 16;
    return (short)r;
}
__device__ __forceinline__ float b2f(unsigned short s) {
    union { float f; unsigned u; } v; v.u = ((unsigned)s) << 16; return v.f;
}

// ---------------- CSR sort helpers ----------------------------------------------
__global__ void k_hist(const int* __restrict__ edst, int* __restrict__ hist) {
    int e = blockIdx.x * 256 + threadIdx.x;
    if (e < E_EDGES) atomicAdd(&hist[edst[e]], 1);
}

// block 0: exclusive scan of hist -> start.  blocks 1..8: mw2 -> frag-linear bf16
__global__ void k_scan_prep(const int* __restrict__ hist, int* __restrict__ start,
                            const float* __restrict__ mw2, __hip_bfloat16* __restrict__ mw2f) {
    __shared__ __align__(16) char sm[4096];
    int b = blockIdx.x, t = threadIdx.x;
    if (b == 0) {
        int* part = (int*)sm;
        int loc[13];
        int s = 0;
#pragma unroll
        for (int j = 0; j < 13; j++) {
            int idx = t * 13 + j;
            int v = (idx < N_NODES) ? hist[idx] : 0;
            loc[j] = s; s += v;
        }
        part[t] = s;
        __syncthreads();
        for (int off = 1; off < 256; off <<= 1) {
            int v = part[t];
            int add = (t >= off) ? part[t - off] : 0;
            __syncthreads();
            part[t] = v + add;
            __syncthreads();
        }
        int pre = (t == 0) ? 0 : part[t - 1];
#pragma unroll
        for (int j = 0; j < 13; j++) {
            int idx = t * 13 + j;
            if (idx < N_NODES) start[idx] = pre + loc[j];
        }
        if (t == 255) start[N_NODES] = part[255];
    } else {
        __hip_bfloat16* st = (__hip_bfloat16*)sm;
        int tt = b - 1;
        for (int idx = t; idx < 2048; idx += 256) {
            int k = idx >> 4, c = idx & 15;
            float v = mw2[k * HID + tt * 16 + c];
            int kk = k >> 5, q4 = (k >> 3) & 3, j = k & 7;
            st[kk * 512 + (q4 * 16 + c) * 8 + j] = __float2bfloat16(v);
        }
        __syncthreads();
        ((bf16x8*)(mw2f + tt * 2048))[t] = ((const bf16x8*)st)[t];
    }
}

// k_scatter: compute perm position AND materialize all per-edge arrays in
// perm (dest-sorted) order, so k_msg reads are coalesced.
__global__ void k_scatter(const int* __restrict__ edst, const int* __restrict__ esrc,
                          const float* __restrict__ esh, const int* __restrict__ start,
                          int* __restrict__ cur, int* __restrict__ inv,
                          int* __restrict__ edstp, int* __restrict__ esrcp,
                          float* __restrict__ eshp) {
    int e = blockIdx.x * 256 + threadIdx.x;
    if (e < E_EDGES) {
        int d = edst[e];
        int pos = start[d] + atomicAdd(&cur[d], 1);
        inv[e] = pos;
        edstp[pos] = d;
        esrcp[pos] = esrc[e];
        f32x4 s = *(const f32x4*)(esh + e * 4);
        *(f32x4*)(eshp + pos * 4) = s;
    }
}

// ---------------- K_front: edge MLP (fused) + mw3 prep + norm -------------------
// h2 output goes to h2p in 16-edge-tiled fragment layout at perm position:
//   h2p[(pos/16)*2048 + (c/8)*128 + (pos%16)*8 + (c%8)]   (bf16 units)
__global__ __launch_bounds__(256) void k_front(
    const float* __restrict__ rbf, const float* __restrict__ elen,
    const int* __restrict__ inv,
    const float* __restrict__ mw1, const float* __restrict__ mb1,
    const float* __restrict__ gw1, const float* __restrict__ gb1,
    const float* __restrict__ gw2, const float* __restrict__ gb2,
    const float* __restrict__ mb2, const __hip_bfloat16* __restrict__ mw2f,
    const float* __restrict__ mw3, const float* __restrict__ mb3,
    const float* __restrict__ x, const float* __restrict__ nw, const float* __restrict__ nb,
    float* __restrict__ ewg, unsigned short* __restrict__ h2p,
    __hip_bfloat16* __restrict__ mw3f, __hip_bfloat16* __restrict__ biasf,
    float* __restrict__ xn, unsigned short* __restrict__ xnb) {
    __shared__ __align__(16) char smem[16640];
    int b = blockIdx.x, tid = threadIdx.x;
    if (b < 782) {
        __hip_bfloat16* h1l = (__hip_bfloat16*)smem;   // [64][128] = 16384 B
        float* gatep = (float*)(smem + 16384);          // [64]
        int wid = __builtin_amdgcn_readfirstlane(tid >> 6);
        int lane = tid & 63;
        int base = b * 64;
        int eb = base + wid * 16;
        // ---- mlp1 (wave: 16 edges x 128 ch) ----
        {
            int c0 = lane, c1 = 64 + lane;
            float t0[16], t1[16], g0[16], g1[16];
            float b0 = mb1[c0], b1 = mb1[c1], gb0v = gb1[c0], gb1v = gb1[c1];
#pragma unroll
            for (int e = 0; e < 16; e++) { t0[e] = b0; t1[e] = b1; g0[e] = gb0v; g1[e] = gb1v; }
#pragma unroll
            for (int r = 0; r < RBFN; r++) {
                float w0 = mw1[r * HID + c0], w1 = mw1[r * HID + c1];
                float v0 = gw1[r * HID + c0], v1 = gw1[r * HID + c1];
#pragma unroll
                for (int e = 0; e < 16; e++) {
                    int ee = eb + e; if (ee >= E_EDGES) ee = E_EDGES - 1;
                    float rv = rbf[ee * RBFN + r];
                    t0[e] += rv * w0; t1[e] += rv * w1;
                    g0[e] += rv * v0; g1[e] += rv * v1;
                }
            }
            float q0 = gw2[c0], q1 = gw2[c1];
            float gb2v = gb2[0];
#pragma unroll
            for (int e = 0; e < 16; e++) {
                int le = wid * 16 + e;
                h1l[le * 128 + c0] = __float2bfloat16(silu_f(t0[e]));
                h1l[le * 128 + c1] = __float2bfloat16(silu_f(t1[e]));
                float p = silu_f(g0[e]) * q0 + silu_f(g1[e]) * q1;
                p += __shfl_xor(p, 1);  p += __shfl_xor(p, 2);  p += __shfl_xor(p, 4);
                p += __shfl_xor(p, 8);  p += __shfl_xor(p, 16); p += __shfl_xor(p, 32);
                if (lane == 0) gatep[le] = p + gb2v;
            }
        }
        __syncthreads();
        // ---- ewg scatter (perm order), 16 lanes per wave in parallel ----
        if (lane < 16) {
            int ee = eb + lane;
            if (ee < E_EDGES) {
                float len = elen[ee];
                float cut = (len <= CUTF) ? 0.5f * (cosf(3.14159265358979f * len / CUTF) + 1.0f) : 0.f;
                ewg[inv[ee]] = cut * sigm(gatep[wid * 16 + lane]);
            }
        }
        // ---- mlp2 (wave: 16 edges, MFMA vs mw2f) ----
        {
            int q4 = lane >> 4, l15 = lane & 15;
            int le = wid * 16 + l15;
            bf16x8 af[4];
#pragma unroll
            for (int kk = 0; kk < 4; kk++)
                af[kk] = *(const bf16x8*)(h1l + le * 128 + kk * 32 + q4 * 8);
            int pos4[4];
#pragma unroll
            for (int r = 0; r < 4; r++) {
                int ge = base + wid * 16 + q4 * 4 + r;
                pos4[r] = (ge < E_EDGES) ? inv[ge] : -1;
            }
            const f32x4 zf = {0.f, 0.f, 0.f, 0.f};
#pragma unroll
            for (int ct = 0; ct < 8; ct++) {
                f32x4 acc = zf;
#pragma unroll
                for (int kk = 0; kk < 4; kk++) {
                    bf16x8 bw = *(const bf16x8*)(mw2f + (ct * 4 + kk) * 512 + lane * 8);
                    acc = __builtin_amdgcn_mfma_f32_16x16x32_bf16(af[kk], bw, acc, 0, 0, 0);
                }
                float bias = mb2[ct * 16 + l15];
                int c = ct * 16 + l15;
                int f = c >> 3, j = c & 7;
#pragma unroll
                for (int r = 0; r < 4; r++) {
                    int pos = pos4[r];
                    if (pos >= 0)
                        h2p[(pos >> 4) * 2048 + f * 128 + (pos & 15) * 8 + j] =
                            (unsigned short)bf16r(silu_f(acc[r] + bias));
                }
            }
        }
    } else if (b < 927) {
        int b2 = b - 782;
        __hip_bfloat16* st = (__hip_bfloat16*)smem;
        if (b2 < 144) {
            for (int idx = tid; idx < 2048; idx += 256) {
                int k = idx >> 4, c = idx & 15;
                float v = mw3[k * WNUM + b2 * 16 + c];
                int kk = k >> 5, q4 = (k >> 3) & 3, j = k & 7;
                st[kk * 512 + (q4 * 16 + c) * 8 + j] = __float2bfloat16(v);
            }
            __syncthreads();
            ((bf16x8*)(mw3f + b2 * 2048))[tid] = ((const bf16x8*)st)[tid];
        } else {
            for (int idx = tid; idx < 3072; idx += 256) {
                float val;
                if (idx < 1024) {
                    int oh = idx >> 9, l = (idx >> 3) & 63, j = idx & 7;
                    int o = oh * 16 + (l & 15), i = (l >> 4) * 8 + j;
                    val = mb3[i * 32 + o];
                } else if (idx < 2048) {
                    int t = idx - 1024;
                    int oh = t >> 9, l = (t >> 3) & 63, j = t & 7;
                    int o = oh * 16 + (l & 15), i = (l >> 4) * 8 + j;
                    val = (i < 16) ? mb3[1024 + i * 32 + o] : 0.f;
                } else if (idx < 2560) {
                    int t = idx - 2048;
                    int l = t >> 3, j = t & 7;
                    int o = l & 15, i = (l >> 4) * 8 + j;
                    val = mb3[1536 + i * 16 + o];
                } else {
                    int t = idx - 2560;
                    int l = t >> 3, j = t & 7;
                    int o = l & 15, i = (l >> 4) * 8 + j;
                    val = (i < 16) ? mb3[2048 + i * 16 + o] : 0.f;
                }
                biasf[idx] = __float2bfloat16(val);
            }
        }
    } else {
        // irrep norm: 4 nodes per block (b in [927, 1727))
        float* row = (float*)smem;   // [4][80]
        int sub = tid >> 6, t = tid & 63;
        int n = (b - 927) * 4 + sub;
        float* rw = row + sub * 80;
        const float* xr = x + n * DD;
        rw[t] = xr[t];
        if (t < 16) rw[64 + t] = xr[64 + t];
        __syncthreads();
        float mean = 0.f;
#pragma unroll
        for (int i = 0; i < NS; i++) mean += rw[i];
        mean *= (1.0f / NS);
        float var = 0.f;
#pragma unroll
        for (int i = 0; i < NS; i++) { float d = rw[i] - mean; var += d * d; }
        var *= (1.0f / NS);
        float inv_ = rsqrtf(var + EPSF);
        if (t < NS) {
            float v = (rw[t] - mean) * inv_ * nw[t] + nb[t];
            xn[n * DD + t] = v;
            xnb[n * DD + t] = (unsigned short)bf16r(v);
        }
        if (t < 48) {
            int j = t / 3;
            float v0 = rw[NS + 3 * j], v1 = rw[NS + 3 * j + 1], v2 = rw[NS + 3 * j + 2];
            float rms = sqrtf((v0 * v0 + v1 * v1 + v2 * v2) * (1.0f / 3.0f) + EPSF);
            float v = rw[NS + t] / rms * nw[NS + t] + nb[NS + t];
            xn[n * DD + NS + t] = v;
            xnb[n * DD + NS + t] = (unsigned short)bf16r(v);
        }
    }
}

// -------- K_msg v18: v17 + deep software pipeline (S 4-deep, V 2-deep) ----------
// v17 post-mortem: XCD swizzle cut FETCH 42->11.4MB but time only -4% ->
// latency-bound with TLP capped (~15% occupancy, immune to LDS/VGPR knobs).
// ILP is the remaining lever: S slices had only 2-deep A-prefetch (~160cyc of
// MFMA vs ~250cyc L2 latency -> residual stall/chunk); V slice had NO prefetch.
// S: rotate 4 register A-sets (explicit unroll, static indexing per rule #20);
// load-to-use distance ~3 computes (~300cyc). V: 2-deep in both phases.
__global__ __launch_bounds__(128, 2) void k_msg(
    const unsigned short* __restrict__ xnb, const unsigned short* __restrict__ h2p,
    const float* __restrict__ ewg, const int* __restrict__ edstp,
    const int* __restrict__ esrcp, const float* __restrict__ eshp,
    const __hip_bfloat16* __restrict__ mw3f, const __hip_bfloat16* __restrict__ biasf,
    const int* __restrict__ startp, float* __restrict__ agg, float* __restrict__ agg2,
    float* __restrict__ den) {
    __shared__ __align__(16) char pool[30720];
    unsigned short (*xng)[88]  = (unsigned short(*)[88])(pool);          // [0,22528)
    unsigned short (*innr)[16] = (unsigned short(*)[16])(pool + 22528);  // [22528,26624)
    float* sh0l = (float*)(pool + 26624);    // 512
    int* srcl   = (int*)(pool + 27136);      // 512
    int* dstl   = (int*)(pool + 27648);      // 512  (persistent)
    float* ewl  = (float*)(pool + 28160);    // 512  (persistent)
    float (*sh1l)[4] = (float(*)[4])(pool + 28672);  // 2048 (persistent)
    float* msgl = (float*)pool;              // epilogue overlay [0,24576) max

    const int tid = threadIdx.x;
    const int wid = __builtin_amdgcn_readfirstlane(tid >> 6);
    const int lane = tid & 63;
    const int q4 = lane >> 4;
    const int l15 = lane & 15;
    const int ib = q4 * 8;
    // XCD-aware bijective swizzle (grid = 1960 = 245 x 8)
    const int xcd = blockIdx.x & 7;
    const int j8 = blockIdx.x >> 3;
    const int grp = xcd + 8 * (j8 / 5);
    const int slice = j8 - 5 * (j8 / 5);
    if (grp >= 391) return;
    const int e0 = grp * 128;

    {   // edge metadata: 128 edges, coalesced perm-ordered reads
        int slot = e0 + tid;
        bool v = slot < E_EDGES;
        dstl[tid] = v ? edstp[slot] : -1;
        srcl[tid] = v ? esrcp[slot] : 0;
        ewl[tid]  = v ? ewg[slot] : 0.f;
        f32x4 s = {0.f, 0.f, 0.f, 0.f};
        if (v) s = *(const f32x4*)(eshp + slot * 4);
        sh0l[tid] = s[0];
        sh1l[tid][0] = s[1]; sh1l[tid][1] = s[2]; sh1l[tid][2] = s[3];
    }
    __syncthreads();
    // ---- per-slice xng staging (bf16 source, 16B-aligned rows) ----
    if (slice < 2) {
        for (int idx = tid; idx < 128 * 4; idx += 128) {   // cols [0,32)
            int e = idx >> 2, q = (idx & 3) * 8;
            *(bf16x8*)&xng[e][q] = *(const bf16x8*)(xnb + srcl[e] * 80 + q);
        }
    } else if (slice < 4) {
        for (int idx = tid; idx < 128 * 7; idx += 128) {   // cols [24,80)
            int e = idx / 7, q = 24 + (idx - e * 7) * 8;
            *(bf16x8*)&xng[e][q] = *(const bf16x8*)(xnb + srcl[e] * 80 + q);
        }
    } else {
        for (int idx = tid; idx < 128 * 10; idx += 128) {  // cols [0,80)
            int e = idx / 10, q = (idx - e * 10) * 8;
            *(bf16x8*)&xng[e][q] = *(const bf16x8*)(xnb + srcl[e] * 80 + q);
        }
    }
    __syncthreads();
    if (slice == 2 || slice == 3) {
        for (int idx = tid; idx < 128 * 16; idx += 128) {
            int e = idx >> 4, i = idx & 15;
            float d = b2f(xng[e][32 + 3 * i]) * sh1l[e][0]
                    + b2f(xng[e][32 + 3 * i + 1]) * sh1l[e][1]
                    + b2f(xng[e][32 + 3 * i + 2]) * sh1l[e][2];
            innr[e][i] = (unsigned short)bf16r(A2ISQ * d);
        }
        __syncthreads();
    }

    // ---- per-wave B-fragments: 4 edge-tiles of 16, 1KB contiguous per load ----
    int el[4];
#pragma unroll
    for (int et = 0; et < 4; et++) el[et] = wid * 64 + et * 16 + l15;
    const int tbase = (e0 >> 4) + wid * 4;
    bf16x8 hfr[4][4];
#pragma unroll
    for (int et = 0; et < 4; et++) {
        const unsigned short* tp = h2p + (tbase + et) * 2048;
#pragma unroll
        for (int kk = 0; kk < 4; kk++)
            hfr[et][kk] = *(const bf16x8*)(tp + (kk * 4 + q4) * 128 + l15 * 8);
    }
    const f32x4 zf = {0.f, 0.f, 0.f, 0.f};
    const bf16x8* gp = (const bf16x8*)mw3f;   // chunk n at gp + n*512
    int cnt = E_EDGES - e0; if (cnt > 128) cnt = 128;

    if (slice < 4) {
        // ============ S quarter: o-half h, chunks [24*ch2, 24*ch2+24) ===========
        const int h = slice & 1;
        const int ch2 = slice >> 1;
        const int nlo = ch2 * 24, nhi = nlo + 24;
        float f1[4];
        f32x4 msgS[4];
#pragma unroll
        for (int et = 0; et < 4; et++) f1[et] = A1C * sh0l[el[et]];
#pragma unroll
        for (int et = 0; et < 4; et++) {
            bf16x8 pb;
            if (ch2 == 0) {
#pragma unroll
                for (int j = 0; j < 8; j++)
                    pb[j] = bf16r(b2f(xng[el[et]][ib + j]) * f1[et]);
            } else {
#pragma unroll
                for (int j = 0; j < 8; j++)
                    pb[j] = (ib + j < 16) ? (short)innr[el[et]][ib + j] : (short)0;
            }
            bf16x8 ba = *(const bf16x8*)(biasf + (ch2 * 1024 + h * 512) + lane * 8);
            msgS[et] = __builtin_amdgcn_mfma_f32_16x16x32_bf16(ba, pb, zf, 0, 0, 0);
        }
        auto computeS = [&](int n, bf16x8 (&A)[4]) {
            f32x4 acc[4];
#pragma unroll
            for (int et = 0; et < 4; et++) acc[et] = zf;
#pragma unroll
            for (int kk = 0; kk < 4; kk++)
#pragma unroll
                for (int et = 0; et < 4; et++)
                    acc[et] = __builtin_amdgcn_mfma_f32_16x16x32_bf16(
                        A[kk], hfr[et][kk], acc[et], 0, 0, 0);
            float p[4];
            if (n < 32) {
#pragma unroll
                for (int et = 0; et < 4; et++) p[et] = f1[et] * b2f(xng[el[et]][n]);
            } else {
#pragma unroll
                for (int et = 0; et < 4; et++) p[et] = b2f(innr[el[et]][n - 32]);
            }
#pragma unroll
            for (int et = 0; et < 4; et++)
#pragma unroll
                for (int r = 0; r < 4; r++)
                    msgS[et][r] += p[et] * acc[et][r];
        };
        // ---- 4-deep register prefetch, no barriers (24 chunks = 6 iters) ----
        bf16x8 A0[4], A1[4], A2[4], A3[4];
        {
            const bf16x8* g0 = gp + (nlo + 0) * 512 + h * 256;
            const bf16x8* g1 = gp + (nlo + 1) * 512 + h * 256;
            const bf16x8* g2 = gp + (nlo + 2) * 512 + h * 256;
            const bf16x8* g3 = gp + (nlo + 3) * 512 + h * 256;
#pragma unroll
            for (int f = 0; f < 4; f++) {
                A0[f] = g0[f * 64 + lane];
                A1[f] = g1[f * 64 + lane];
                A2[f] = g2[f * 64 + lane];
                A3[f] = g3[f * 64 + lane];
            }
        }
        for (int n = nlo; n < nhi; n += 4) {
            computeS(n, A0);
            if (n + 4 < nhi) {
                const bf16x8* g = gp + (n + 4) * 512 + h * 256;
#pragma unroll
                for (int f = 0; f < 4; f++) A0[f] = g[f * 64 + lane];
            }
            computeS(n + 1, A1);
            if (n + 5 < nhi) {
                const bf16x8* g = gp + (n + 5) * 512 + h * 256;
#pragma unroll
                for (int f = 0; f < 4; f++) A1[f] = g[f * 64 + lane];
            }
            computeS(n + 2, A2);
            if (n + 6 < nhi) {
                const bf16x8* g = gp + (n + 6) * 512 + h * 256;
#pragma unroll
                for (int f = 0; f < 4; f++) A2[f] = g[f * 64 + lane];
            }
            computeS(n + 3, A3);
            if (n + 7 < nhi) {
                const bf16x8* g = gp + (n + 7) * 512 + h * 256;
#pragma unroll
                for (int f = 0; f < 4; f++) A3[f] = g[f * 64 + lane];
            }
        }
        // ---- epilogue: 16 channels (+den for s0), single-writer ----
        __syncthreads();
#pragma unroll
        for (int et = 0; et < 4; et++) {
            int le = el[et];
            float ew = ewl[le];
#pragma unroll
            for (int r = 0; r < 4; r++)
                msgl[le * 16 + q4 * 4 + r] = msgS[et][r] * ew;
        }
        __syncthreads();
        {
            int nch = (slice == 0) ? 17 : 16;
            int c = lane;
            int r0 = wid * 64;
            int rend = (cnt < r0 + 64) ? cnt : (r0 + 64);
            if (c < nch && r0 < cnt) {
                int cur = dstl[r0];
                float acc = 0.f;
                for (int r = r0; r < rend; r++) {
                    int nd = dstl[r];
                    if (nd != cur) {
                        if (cur >= 0) {
                            bool interior = (startp[cur] >= e0 + r0) && (startp[cur + 1] <= e0 + rend);
                            float* p = (c == 16) ? (den + cur)
                                     : ((slice == 0) ? (agg + cur * 80 + c)
                                     :  (slice == 1) ? (agg + cur * 80 + 16 + c)
                                     :  (slice == 2) ? (agg2 + cur * 32 + c)
                                                     : (agg2 + cur * 32 + 16 + c));
                            if (interior) *p = acc; else atomicAdd(p, acc);
                        }
                        acc = 0.f; cur = nd;
                    }
                    acc += (c == 16) ? ewl[r] : msgl[r * 16 + c];
                }
                if (cur >= 0) {
                    bool interior = (startp[cur] >= e0 + r0) && (startp[cur + 1] <= e0 + rend);
                    float* p = (c == 16) ? (den + cur)
                             : ((slice == 0) ? (agg + cur * 80 + c)
                             :  (slice == 1) ? (agg + cur * 80 + 16 + c)
                             :  (slice == 2) ? (agg2 + cur * 32 + c)
                                             : (agg2 + cur * 32 + 16 + c));
                    if (interior) *p = acc; else atomicAdd(p, acc);
                }
            }
        }
    } else {
        // ============ V slice: q3 phase [48,64) then qv phase [64,72) ===========
        float f4e[4];
#pragma unroll
        for (int et = 0; et < 4; et++) f4e[et] = A4C * sh0l[el[et]];
        // --- phase 1: q3 (w3), bias ba3, 2-deep prefetch ---
        f32x4 q3[4];
#pragma unroll
        for (int et = 0; et < 4; et++) {
            bf16x8 xs8;
#pragma unroll
            for (int j = 0; j < 8; j++) xs8[j] = (short)xng[el[et]][ib + j];
            bf16x8 ba3 = *(const bf16x8*)(biasf + 2048 + lane * 8);
            q3[et] = __builtin_amdgcn_mfma_f32_16x16x32_bf16(ba3, xs8, zf, 0, 0, 0);
        }
        auto computeQ3 = [&](int n, bf16x8 (&A)[8]) {
#pragma unroll
            for (int half = 0; half < 2; half++) {
                f32x4 acc[4];
#pragma unroll
                for (int et = 0; et < 4; et++) acc[et] = zf;
#pragma unroll
                for (int kk = 0; kk < 4; kk++)
#pragma unroll
                    for (int et = 0; et < 4; et++)
                        acc[et] = __builtin_amdgcn_mfma_f32_16x16x32_bf16(
                            A[half * 4 + kk], hfr[et][kk], acc[et], 0, 0, 0);
                int i = 2 * (n - 48) + half;
                float p[4];
#pragma unroll
                for (int et = 0; et < 4; et++) p[et] = b2f(xng[el[et]][i]);
#pragma unroll
                for (int et = 0; et < 4; et++)
#pragma unroll
                    for (int r = 0; r < 4; r++)
                        q3[et][r] += p[et] * acc[et][r];
            }
        };
        {
            bf16x8 B0[8], B1[8];
            const bf16x8* g0 = gp + 48 * 512;
            const bf16x8* g1 = gp + 49 * 512;
#pragma unroll
            for (int f = 0; f < 8; f++) { B0[f] = g0[f * 64 + lane]; B1[f] = g1[f * 64 + lane]; }
            for (int n = 48; n < 64; n += 2) {
                computeQ3(n, B0);
                if (n + 2 < 64) {
                    const bf16x8* g = gp + (n + 2) * 512;
#pragma unroll
                    for (int f = 0; f < 8; f++) B0[f] = g[f * 64 + lane];
                }
                computeQ3(n + 1, B1);
                if (n + 3 < 64) {
                    const bf16x8* g = gp + (n + 3) * 512;
#pragma unroll
                    for (int f = 0; f < 8; f++) B1[f] = g[f * 64 + lane];
                }
            }
        }
        // --- phase 2: qv (w4), bias ba4, 2-deep prefetch ---
        f32x4 qv[3][4];
#pragma unroll
        for (int et = 0; et < 4; et++) {
            bf16x8 ba4 = *(const bf16x8*)(biasf + 2560 + lane * 8);
#pragma unroll
            for (int m = 0; m < 3; m++) {
                bf16x8 t8;
#pragma unroll
                for (int j = 0; j < 8; j++) {
                    int i = ib + j;
                    t8[j] = (i < 16) ? (short)xng[el[et]][32 + 3 * i + m] : (short)0;
                }
                qv[m][et] = __builtin_amdgcn_mfma_f32_16x16x32_bf16(ba4, t8, zf, 0, 0, 0);
            }
        }
        auto computeQV = [&](int n, bf16x8 (&A)[8]) {
#pragma unroll
            for (int half = 0; half < 2; half++) {
                f32x4 acc[4];
#pragma unroll
                for (int et = 0; et < 4; et++) acc[et] = zf;
#pragma unroll
                for (int kk = 0; kk < 4; kk++)
#pragma unroll
                    for (int et = 0; et < 4; et++)
                        acc[et] = __builtin_amdgcn_mfma_f32_16x16x32_bf16(
                            A[half * 4 + kk], hfr[et][kk], acc[et], 0, 0, 0);
                int i = 2 * (n - 64) + half;
#pragma unroll
                for (int m = 0; m < 3; m++) {
                    float p[4];
#pragma unroll
                    for (int et = 0; et < 4; et++) p[et] = b2f(xng[el[et]][32 + 3 * i + m]);
#pragma unroll
                    for (int et = 0; et < 4; et++)
#pragma unroll
                        for (int r = 0; r < 4; r++)
                            qv[m][et][r] += p[et] * acc[et][r];
                }
            }
        };
        {
            bf16x8 B0[8], B1[8];
            const bf16x8* g0 = gp + 64 * 512;
            const bf16x8* g1 = gp + 65 * 512;
#pragma unroll
            for (int f = 0; f < 8; f++) { B0[f] = g0[f * 64 + lane]; B1[f] = g1[f * 64 + lane]; }
            for (int n = 64; n < 72; n += 2) {
                computeQV(n, B0);
                if (n + 2 < 72) {
                    const bf16x8* g = gp + (n + 2) * 512;
#pragma unroll
                    for (int f = 0; f < 8; f++) B0[f] = g[f * 64 + lane];
                }
                computeQV(n + 1, B1);
                if (n + 3 < 72) {
                    const bf16x8* g = gp + (n + 3) * 512;
#pragma unroll
                    for (int f = 0; f < 8; f++) B1[f] = g[f * 64 + lane];
                }
            }
        }
        // ---- epilogue: 48 V channels, single-writer ----
        __syncthreads();
#pragma unroll
        for (int et = 0; et < 4; et++) {
            int le = el[et];
            float ew = ewl[le];
            float s0 = sh1l[le][0], s1 = sh1l[le][1], s2 = sh1l[le][2];
            float b4 = f4e[et];
#pragma unroll
            for (int r = 0; r < 4; r++) {
                int o = q4 * 4 + r;
                float qq = A3C * q3[et][r];
                msgl[le * 48 + o * 3 + 0] = (qq * s0 + b4 * qv[0][et][r]) * ew;
                msgl[le * 48 + o * 3 + 1] = (qq * s1 + b4 * qv[1][et][r]) * ew;
                msgl[le * 48 + o * 3 + 2] = (qq * s2 + b4 * qv[2][et][r]) * ew;
            }
        }
        __syncthreads();
        {
            int c = lane;
            int r0 = wid * 64;
            int rend = (cnt < r0 + 64) ? cnt : (r0 + 64);
            if (c < 48 && r0 < cnt) {
                int cur = dstl[r0];
                float acc = 0.f;
                for (int r = r0; r < rend; r++) {
                    int nd = dstl[r];
                    if (nd != cur) {
                        if (cur >= 0) {
                            bool interior = (startp[cur] >= e0 + r0) && (startp[cur + 1] <= e0 + rend);
                            float* p = agg + cur * 80 + 32 + c;
                            if (interior) *p = acc; else atomicAdd(p, acc);
                        }
                        acc = 0.f; cur = nd;
                    }
                    acc += msgl[r * 48 + c];
                }
                if (cur >= 0) {
                    bool interior = (startp[cur] >= e0 + r0) && (startp[cur + 1] <= e0 + rend);
                    float* p = agg + cur * 80 + 32 + c;
                    if (interior) *p = acc; else atomicAdd(p, acc);
                }
            }
        }
    }
}

// ---------------- K_update: per-node update, 4 nodes/block ----------------------
__global__ __launch_bounds__(256) void k_update(
    const float* __restrict__ x, const float* __restrict__ xn,
    const float* __restrict__ agg, const float* __restrict__ agg2,
    const float* __restrict__ den,
    const float* __restrict__ Ws, const float* __restrict__ Wv,
    const float* __restrict__ Us, const float* __restrict__ Uv,
    const float* __restrict__ Ss, const float* __restrict__ Sv,
    const float* __restrict__ rsp, float* __restrict__ out) {
    int sub = threadIdx.x >> 6, t = threadIdx.x & 63;
    int n = blockIdx.x * 4 + sub;
    __shared__ float ag[4][DD];
    __shared__ float xnl[4][DD];
    __shared__ float sg[4][NS];
    __shared__ float gt[4][NV];
    __shared__ float vg[4][48];
    float idv = 1.0f / fmaxf(den[n], 1e-8f);
    float base = agg[n * DD + t];
    if (t < 32) base += agg2[n * 32 + t];
    ag[sub][t] = base * idv;
    if (t < 16) ag[sub][64 + t] = agg[n * DD + 64 + t] * idv;
    xnl[sub][t] = xn[n * DD + t];
    if (t < 16) xnl[sub][64 + t] = xn[n * DD + 64 + t];
    __syncthreads();
    const float iqs = 0.17677669529663687f;
    const float iqv = 0.25f;
    if (t < 48) {
        float acc = 0.f;
#pragma unroll
        for (int i = 0; i < NS; i++) acc += ag[sub][i] * Ws[i * 48 + t];
        acc *= iqs;
        if (t < NS) sg[sub][t] = silu_f(acc);
        else gt[sub][t - NS] = sigm(acc);
    }
    __syncthreads();
    if (t < 48) {
        int o = t / 3, m = t - 3 * o;
        float acc = 0.f;
#pragma unroll
        for (int i = 0; i < NV; i++) acc += ag[sub][NS + 3 * i + m] * Wv[i * NV + o];
        vg[sub][t] = acc * iqv * gt[sub][o];
    }
    __syncthreads();
    float rs = rsp[0];
    if (t < NS) {
        float us = 0.f, ss = 0.f;
#pragma unroll
        for (int i = 0; i < NS; i++) { us += sg[sub][i] * Us[i * NS + t]; ss += xnl[sub][i] * Ss[i * NS + t]; }
        out[n * DD + t] = x[n * DD + t] + rs * ((ss + us) * iqs);
    }
    if (t < 48) {
        int o = t / 3, m = t - 3 * o;
        float uv = 0.f, sv = 0.f;
#pragma unroll
        for (int i = 0; i < NV; i++) { uv += vg[sub][3 * i + m] * Uv[i * NV + o]; sv += xnl[sub][NS + 3 * i + m] * Sv[i * NV + o]; }
        out[n * DD + NS + t] = x[n * DD + NS + t] + rs * ((sv + uv) * iqv);
    }
}

extern "C" void kernel_launch(void* const* d_in, const int* in_sizes, int n_in,
                              void* d_out, int out_size, void* d_ws, size_t ws_size,
                              hipStream_t stream) {
    (void)in_sizes; (void)n_in; (void)out_size; (void)ws_size;
    const float* x    = (const float*)d_in[0];
    const int*   esrc = (const int*)d_in[1];
    const int*   edst = (const int*)d_in[2];
    const float* esh  = (const float*)d_in[3];
    const float* erbf = (const float*)d_in[4];
    const float* elen = (const float*)d_in[5];
    const float* nw   = (const float*)d_in[6];
    const float* nb   = (const float*)d_in[7];
    const float* mw1  = (const float*)d_in[8];
    const float* mb1  = (const float*)d_in[9];
    const float* mw2  = (const float*)d_in[10];
    const float* mb2  = (const float*)d_in[11];
    const float* mw3  = (const float*)d_in[12];
    const float* mb3  = (const float*)d_in[13];
    const float* gw1  = (const float*)d_in[14];
    const float* gb1  = (const float*)d_in[15];
    const float* gw2  = (const float*)d_in[16];
    const float* gb2  = (const float*)d_in[17];
    const float* Ws   = (const float*)d_in[18];
    const float* Wv   = (const float*)d_in[19];
    const float* Us   = (const float*)d_in[20];
    const float* Uv   = (const float*)d_in[21];
    const float* Ss   = (const float*)d_in[22];
    const float* Sv   = (const float*)d_in[23];
    const float* rsp  = (const float*)d_in[24];
    float* out = (float*)d_out;
    float* ws  = (float*)d_ws;

    // ws layout (float offsets); [0, 368000) zeroed in ONE memset:
    //   agg[0,256000) den[256000,259200) agg2[259200,361600)
    //   hist[361600,364800) cur[364800,368000)
    float* agg    = ws;
    float* den    = ws + 256000;
    float* agg2   = ws + 259200;
    int*   hist   = (int*)(ws + 361600);
    int*   cur    = (int*)(ws + 364800);
    int*   startp = (int*)(ws + 368000);       // 3201
    int*   inv    = (int*)(ws + 371204);       // 50000
    float* xn     = ws + 421204;               // 256000
    float* ewg    = ws + 677204;               // 50000 (perm-ordered)
    unsigned short* h2p = (unsigned short*)(ws + 727204);     // 6406144 bf16 (tiled)
    __hip_bfloat16* mw3f  = (__hip_bfloat16*)(ws + 3930276);  // 294912 bf16
    __hip_bfloat16* biasf = (__hip_bfloat16*)(ws + 4077732);  // 3072 bf16
    __hip_bfloat16* mw2f  = (__hip_bfloat16*)(ws + 4079268);  // 16384 bf16
    int* edstp    = (int*)(ws + 4087460);      // 50048
    int* esrcp    = (int*)(ws + 4137508);      // 50048
    float* eshp   = ws + 4187556;              // 200192 ([50048][4])
    unsigned short* xnb = (unsigned short*)(ws + 4387748);    // 256000 bf16
    // total: 4,515,748 floats ~= 18.1 MB

    hipMemsetAsync(ws, 0, 368000 * sizeof(float), stream);    // agg+den+agg2+hist+cur
    k_hist<<<196, 256, 0, stream>>>(edst, hist);
    k_scan_prep<<<9, 256, 0, stream>>>(hist, startp, mw2, mw2f);
    k_scatter<<<196, 256, 0, stream>>>(edst, esrc, esh, startp, cur,
                                       inv, edstp, esrcp, eshp);
    k_front<<<1727, 256, 0, stream>>>(erbf, elen, inv, mw1, mb1, gw1, gb1, gw2, gb2,
                                      mb2, mw2f, mw3, mb3, x, nw, nb,
                                      ewg, h2p, mw3f, biasf, xn, xnb);
    k_msg<<<1960, 128, 0, stream>>>(xnb, h2p, ewg, edstp, esrcp, eshp,
                                    mw3f, biasf, startp, agg, agg2, den);
    k_update<<<800, 256, 0, stream>>>(x, xn, agg, agg2, den, Ws, Wv, Us, Uv, Ss, Sv, rsp, out);
}

// Round 13
// 228.266 us; speedup vs baseline: 1.5654x; 1.5654x over previous
//
#include <hip/hip_runtime.h>
#include <hip/hip_bf16.h>
#include <math.h>

#define N_NODES 3200
#define E_EDGES 50000
#define RBFN 16
#define HID 128
#define NS 32
#define NV 16
#define DD 80
#define WNUM 2304
#define CUTF 5.0f
#define EPSF 1e-8f

#define A1C 0.125f                  // 1/sqrt(2*NS)
#define A2C 0.17677669529663687f    // 1/sqrt(2*NV)
#define A3C 0.125f
#define A4C 0.17677669529663687f
#define A2ISQ 0.10206207261596575f  // A2C / sqrt(3)

typedef __attribute__((ext_vector_type(4))) float f32x4;
typedef __attribute__((ext_vector_type(8))) short bf16x8;

__device__ __forceinline__ float sigm(float x) { return 1.0f / (1.0f + __expf(-x)); }
__device__ __forceinline__ float silu_f(float x) { return x * sigm(x); }

__device__ __forceinline__ short bf16r(float x) {
    union { float f; unsigned u; } v; v.f = x;
    unsigned r = (v.u + 0x7fffu + ((v.u >> 16) & 1u)) >> 16;
    return (short)r;
}
__device__ __forceinline__ float b2f(unsigned short s) {
    union { float f; unsigned u; } v; v.u = ((unsigned)s) << 16; return v.f;
}

// ---------------- CSR sort helpers ----------------------------------------------
__global__ void k_hist(const int* __restrict__ edst, int* __restrict__ hist) {
    int e = blockIdx.x * 256 + threadIdx.x;
    if (e < E_EDGES) atomicAdd(&hist[edst[e]], 1);
}

// block 0: exclusive scan of hist -> start.  blocks 1..8: mw2 -> frag-linear bf16
__global__ void k_scan_prep(const int* __restrict__ hist, int* __restrict__ start,
                            const float* __restrict__ mw2, __hip_bfloat16* __restrict__ mw2f) {
    __shared__ __align__(16) char sm[4096];
    int b = blockIdx.x, t = threadIdx.x;
    if (b == 0) {
        int* part = (int*)sm;
        int loc[13];
        int s = 0;
#pragma unroll
        for (int j = 0; j < 13; j++) {
            int idx = t * 13 + j;
            int v = (idx < N_NODES) ? hist[idx] : 0;
            loc[j] = s; s += v;
        }
        part[t] = s;
        __syncthreads();
        for (int off = 1; off < 256; off <<= 1) {
            int v = part[t];
            int add = (t >= off) ? part[t - off] : 0;
            __syncthreads();
            part[t] = v + add;
            __syncthreads();
        }
        int pre = (t == 0) ? 0 : part[t - 1];
#pragma unroll
        for (int j = 0; j < 13; j++) {
            int idx = t * 13 + j;
            if (idx < N_NODES) start[idx] = pre + loc[j];
        }
        if (t == 255) start[N_NODES] = part[255];
    } else {
        __hip_bfloat16* st = (__hip_bfloat16*)sm;
        int tt = b - 1;
        for (int idx = t; idx < 2048; idx += 256) {
            int k = idx >> 4, c = idx & 15;
            float v = mw2[k * HID + tt * 16 + c];
            int kk = k >> 5, q4 = (k >> 3) & 3, j = k & 7;
            st[kk * 512 + (q4 * 16 + c) * 8 + j] = __float2bfloat16(v);
        }
        __syncthreads();
        ((bf16x8*)(mw2f + tt * 2048))[t] = ((const bf16x8*)st)[t];
    }
}

// k_scatter: compute perm position AND materialize all per-edge arrays in
// perm (dest-sorted) order, so k_msg reads are coalesced.
__global__ void k_scatter(const int* __restrict__ edst, const int* __restrict__ esrc,
                          const float* __restrict__ esh, const int* __restrict__ start,
                          int* __restrict__ cur, int* __restrict__ inv,
                          int* __restrict__ edstp, int* __restrict__ esrcp,
                          float* __restrict__ eshp) {
    int e = blockIdx.x * 256 + threadIdx.x;
    if (e < E_EDGES) {
        int d = edst[e];
        int pos = start[d] + atomicAdd(&cur[d], 1);
        inv[e] = pos;
        edstp[pos] = d;
        esrcp[pos] = esrc[e];
        f32x4 s = *(const f32x4*)(esh + e * 4);
        *(f32x4*)(eshp + pos * 4) = s;
    }
}

// ---------------- K_front: edge MLP (fused) + mw3 prep + norm -------------------
// h2 output goes to h2p in 16-edge-tiled fragment layout at perm position:
//   h2p[(pos/16)*2048 + (c/8)*128 + (pos%16)*8 + (c%8)]   (bf16 units)
__global__ __launch_bounds__(256) void k_front(
    const float* __restrict__ rbf, const float* __restrict__ elen,
    const int* __restrict__ inv,
    const float* __restrict__ mw1, const float* __restrict__ mb1,
    const float* __restrict__ gw1, const float* __restrict__ gb1,
    const float* __restrict__ gw2, const float* __restrict__ gb2,
    const float* __restrict__ mb2, const __hip_bfloat16* __restrict__ mw2f,
    const float* __restrict__ mw3, const float* __restrict__ mb3,
    const float* __restrict__ x, const float* __restrict__ nw, const float* __restrict__ nb,
    float* __restrict__ ewg, unsigned short* __restrict__ h2p,
    __hip_bfloat16* __restrict__ mw3f, __hip_bfloat16* __restrict__ biasf,
    float* __restrict__ xn, unsigned short* __restrict__ xnb) {
    __shared__ __align__(16) char smem[16640];
    int b = blockIdx.x, tid = threadIdx.x;
    if (b < 782) {
        __hip_bfloat16* h1l = (__hip_bfloat16*)smem;   // [64][128] = 16384 B
        float* gatep = (float*)(smem + 16384);          // [64]
        int wid = __builtin_amdgcn_readfirstlane(tid >> 6);
        int lane = tid & 63;
        int base = b * 64;
        int eb = base + wid * 16;
        // ---- mlp1 (wave: 16 edges x 128 ch) ----
        {
            int c0 = lane, c1 = 64 + lane;
            float t0[16], t1[16], g0[16], g1[16];
            float b0 = mb1[c0], b1 = mb1[c1], gb0v = gb1[c0], gb1v = gb1[c1];
#pragma unroll
            for (int e = 0; e < 16; e++) { t0[e] = b0; t1[e] = b1; g0[e] = gb0v; g1[e] = gb1v; }
#pragma unroll
            for (int r = 0; r < RBFN; r++) {
                float w0 = mw1[r * HID + c0], w1 = mw1[r * HID + c1];
                float v0 = gw1[r * HID + c0], v1 = gw1[r * HID + c1];
#pragma unroll
                for (int e = 0; e < 16; e++) {
                    int ee = eb + e; if (ee >= E_EDGES) ee = E_EDGES - 1;
                    float rv = rbf[ee * RBFN + r];
                    t0[e] += rv * w0; t1[e] += rv * w1;
                    g0[e] += rv * v0; g1[e] += rv * v1;
                }
            }
            float q0 = gw2[c0], q1 = gw2[c1];
            float gb2v = gb2[0];
#pragma unroll
            for (int e = 0; e < 16; e++) {
                int le = wid * 16 + e;
                h1l[le * 128 + c0] = __float2bfloat16(silu_f(t0[e]));
                h1l[le * 128 + c1] = __float2bfloat16(silu_f(t1[e]));
                float p = silu_f(g0[e]) * q0 + silu_f(g1[e]) * q1;
                p += __shfl_xor(p, 1);  p += __shfl_xor(p, 2);  p += __shfl_xor(p, 4);
                p += __shfl_xor(p, 8);  p += __shfl_xor(p, 16); p += __shfl_xor(p, 32);
                if (lane == 0) gatep[le] = p + gb2v;
            }
        }
        __syncthreads();
        // ---- ewg scatter (perm order), 16 lanes per wave in parallel ----
        if (lane < 16) {
            int ee = eb + lane;
            if (ee < E_EDGES) {
                float len = elen[ee];
                float cut = (len <= CUTF) ? 0.5f * (cosf(3.14159265358979f * len / CUTF) + 1.0f) : 0.f;
                ewg[inv[ee]] = cut * sigm(gatep[wid * 16 + lane]);
            }
        }
        // ---- mlp2 (wave: 16 edges, MFMA vs mw2f) ----
        {
            int q4 = lane >> 4, l15 = lane & 15;
            int le = wid * 16 + l15;
            bf16x8 af[4];
#pragma unroll
            for (int kk = 0; kk < 4; kk++)
                af[kk] = *(const bf16x8*)(h1l + le * 128 + kk * 32 + q4 * 8);
            int pos4[4];
#pragma unroll
            for (int r = 0; r < 4; r++) {
                int ge = base + wid * 16 + q4 * 4 + r;
                pos4[r] = (ge < E_EDGES) ? inv[ge] : -1;
            }
            const f32x4 zf = {0.f, 0.f, 0.f, 0.f};
#pragma unroll
            for (int ct = 0; ct < 8; ct++) {
                f32x4 acc = zf;
#pragma unroll
                for (int kk = 0; kk < 4; kk++) {
                    bf16x8 bw = *(const bf16x8*)(mw2f + (ct * 4 + kk) * 512 + lane * 8);
                    acc = __builtin_amdgcn_mfma_f32_16x16x32_bf16(af[kk], bw, acc, 0, 0, 0);
                }
                float bias = mb2[ct * 16 + l15];
                int c = ct * 16 + l15;
                int f = c >> 3, j = c & 7;
#pragma unroll
                for (int r = 0; r < 4; r++) {
                    int pos = pos4[r];
                    if (pos >= 0)
                        h2p[(pos >> 4) * 2048 + f * 128 + (pos & 15) * 8 + j] =
                            (unsigned short)bf16r(silu_f(acc[r] + bias));
                }
            }
        }
    } else if (b < 927) {
        int b2 = b - 782;
        __hip_bfloat16* st = (__hip_bfloat16*)smem;
        if (b2 < 144) {
            for (int idx = tid; idx < 2048; idx += 256) {
                int k = idx >> 4, c = idx & 15;
                float v = mw3[k * WNUM + b2 * 16 + c];
                int kk = k >> 5, q4 = (k >> 3) & 3, j = k & 7;
                st[kk * 512 + (q4 * 16 + c) * 8 + j] = __float2bfloat16(v);
            }
            __syncthreads();
            ((bf16x8*)(mw3f + b2 * 2048))[tid] = ((const bf16x8*)st)[tid];
        } else {
            for (int idx = tid; idx < 3072; idx += 256) {
                float val;
                if (idx < 1024) {
                    int oh = idx >> 9, l = (idx >> 3) & 63, j = idx & 7;
                    int o = oh * 16 + (l & 15), i = (l >> 4) * 8 + j;
                    val = mb3[i * 32 + o];
                } else if (idx < 2048) {
                    int t = idx - 1024;
                    int oh = t >> 9, l = (t >> 3) & 63, j = t & 7;
                    int o = oh * 16 + (l & 15), i = (l >> 4) * 8 + j;
                    val = (i < 16) ? mb3[1024 + i * 32 + o] : 0.f;
                } else if (idx < 2560) {
                    int t = idx - 2048;
                    int l = t >> 3, j = t & 7;
                    int o = l & 15, i = (l >> 4) * 8 + j;
                    val = mb3[1536 + i * 16 + o];
                } else {
                    int t = idx - 2560;
                    int l = t >> 3, j = t & 7;
                    int o = l & 15, i = (l >> 4) * 8 + j;
                    val = (i < 16) ? mb3[2048 + i * 16 + o] : 0.f;
                }
                biasf[idx] = __float2bfloat16(val);
            }
        }
    } else {
        // irrep norm: 4 nodes per block (b in [927, 1727))
        float* row = (float*)smem;   // [4][80]
        int sub = tid >> 6, t = tid & 63;
        int n = (b - 927) * 4 + sub;
        float* rw = row + sub * 80;
        const float* xr = x + n * DD;
        rw[t] = xr[t];
        if (t < 16) rw[64 + t] = xr[64 + t];
        __syncthreads();
        float mean = 0.f;
#pragma unroll
        for (int i = 0; i < NS; i++) mean += rw[i];
        mean *= (1.0f / NS);
        float var = 0.f;
#pragma unroll
        for (int i = 0; i < NS; i++) { float d = rw[i] - mean; var += d * d; }
        var *= (1.0f / NS);
        float inv_ = rsqrtf(var + EPSF);
        if (t < NS) {
            float v = (rw[t] - mean) * inv_ * nw[t] + nb[t];
            xn[n * DD + t] = v;
            xnb[n * DD + t] = (unsigned short)bf16r(v);
        }
        if (t < 48) {
            int j = t / 3;
            float v0 = rw[NS + 3 * j], v1 = rw[NS + 3 * j + 1], v2 = rw[NS + 3 * j + 2];
            float rms = sqrtf((v0 * v0 + v1 * v1 + v2 * v2) * (1.0f / 3.0f) + EPSF);
            float v = rw[NS + t] / rms * nw[NS + t] + nb[NS + t];
            xn[n * DD + NS + t] = v;
            xnb[n * DD + NS + t] = (unsigned short)bf16r(v);
        }
    }
}

// -------- K_msg v19 == v17 (proven 68.1 us): 5 slices + XCD swizzle -------------
// v18 post-mortem: 4-deep S + 2-deep V pipeline -> scratch spill (WRITE 348MB,
// k_msg 200us). REVERTED byte-exact to v17: 2-deep S prefetch, plain V loop,
// 116 VGPR, XCD-aware group swizzle (FETCH 11.4MB).
__global__ __launch_bounds__(128, 2) void k_msg(
    const unsigned short* __restrict__ xnb, const unsigned short* __restrict__ h2p,
    const float* __restrict__ ewg, const int* __restrict__ edstp,
    const int* __restrict__ esrcp, const float* __restrict__ eshp,
    const __hip_bfloat16* __restrict__ mw3f, const __hip_bfloat16* __restrict__ biasf,
    const int* __restrict__ startp, float* __restrict__ agg, float* __restrict__ agg2,
    float* __restrict__ den) {
    __shared__ __align__(16) char pool[30720];
    unsigned short (*xng)[88]  = (unsigned short(*)[88])(pool);          // [0,22528)
    unsigned short (*innr)[16] = (unsigned short(*)[16])(pool + 22528);  // [22528,26624)
    float* sh0l = (float*)(pool + 26624);    // 512
    int* srcl   = (int*)(pool + 27136);      // 512
    int* dstl   = (int*)(pool + 27648);      // 512  (persistent)
    float* ewl  = (float*)(pool + 28160);    // 512  (persistent)
    float (*sh1l)[4] = (float(*)[4])(pool + 28672);  // 2048 (persistent)
    float* msgl = (float*)pool;              // epilogue overlay [0,24576) max

    const int tid = threadIdx.x;
    const int wid = __builtin_amdgcn_readfirstlane(tid >> 6);
    const int lane = tid & 63;
    const int q4 = lane >> 4;
    const int l15 = lane & 15;
    const int ib = q4 * 8;
    // XCD-aware bijective swizzle (grid = 1960 = 245 x 8)
    const int xcd = blockIdx.x & 7;
    const int j8 = blockIdx.x >> 3;
    const int grp = xcd + 8 * (j8 / 5);
    const int slice = j8 - 5 * (j8 / 5);
    if (grp >= 391) return;
    const int e0 = grp * 128;

    {   // edge metadata: 128 edges, coalesced perm-ordered reads
        int slot = e0 + tid;
        bool v = slot < E_EDGES;
        dstl[tid] = v ? edstp[slot] : -1;
        srcl[tid] = v ? esrcp[slot] : 0;
        ewl[tid]  = v ? ewg[slot] : 0.f;
        f32x4 s = {0.f, 0.f, 0.f, 0.f};
        if (v) s = *(const f32x4*)(eshp + slot * 4);
        sh0l[tid] = s[0];
        sh1l[tid][0] = s[1]; sh1l[tid][1] = s[2]; sh1l[tid][2] = s[3];
    }
    __syncthreads();
    // ---- per-slice xng staging (bf16 source, 16B-aligned rows) ----
    if (slice < 2) {
        for (int idx = tid; idx < 128 * 4; idx += 128) {   // cols [0,32)
            int e = idx >> 2, q = (idx & 3) * 8;
            *(bf16x8*)&xng[e][q] = *(const bf16x8*)(xnb + srcl[e] * 80 + q);
        }
    } else if (slice < 4) {
        for (int idx = tid; idx < 128 * 7; idx += 128) {   // cols [24,80)
            int e = idx / 7, q = 24 + (idx - e * 7) * 8;
            *(bf16x8*)&xng[e][q] = *(const bf16x8*)(xnb + srcl[e] * 80 + q);
        }
    } else {
        for (int idx = tid; idx < 128 * 10; idx += 128) {  // cols [0,80)
            int e = idx / 10, q = (idx - e * 10) * 8;
            *(bf16x8*)&xng[e][q] = *(const bf16x8*)(xnb + srcl[e] * 80 + q);
        }
    }
    __syncthreads();
    if (slice == 2 || slice == 3) {
        for (int idx = tid; idx < 128 * 16; idx += 128) {
            int e = idx >> 4, i = idx & 15;
            float d = b2f(xng[e][32 + 3 * i]) * sh1l[e][0]
                    + b2f(xng[e][32 + 3 * i + 1]) * sh1l[e][1]
                    + b2f(xng[e][32 + 3 * i + 2]) * sh1l[e][2];
            innr[e][i] = (unsigned short)bf16r(A2ISQ * d);
        }
        __syncthreads();
    }

    // ---- per-wave B-fragments: 4 edge-tiles of 16, 1KB contiguous per load ----
    int el[4];
#pragma unroll
    for (int et = 0; et < 4; et++) el[et] = wid * 64 + et * 16 + l15;
    const int tbase = (e0 >> 4) + wid * 4;
    bf16x8 hfr[4][4];
#pragma unroll
    for (int et = 0; et < 4; et++) {
        const unsigned short* tp = h2p + (tbase + et) * 2048;
#pragma unroll
        for (int kk = 0; kk < 4; kk++)
            hfr[et][kk] = *(const bf16x8*)(tp + (kk * 4 + q4) * 128 + l15 * 8);
    }
    const f32x4 zf = {0.f, 0.f, 0.f, 0.f};
    const bf16x8* gp = (const bf16x8*)mw3f;   // chunk n at gp + n*512
    int cnt = E_EDGES - e0; if (cnt > 128) cnt = 128;

    if (slice < 4) {
        // ============ S quarter: o-half h, chunks [24*ch2, 24*ch2+24) ===========
        const int h = slice & 1;
        const int ch2 = slice >> 1;
        const int nlo = ch2 * 24, nhi = nlo + 24;
        float f1[4];
        f32x4 msgS[4];
#pragma unroll
        for (int et = 0; et < 4; et++) f1[et] = A1C * sh0l[el[et]];
#pragma unroll
        for (int et = 0; et < 4; et++) {
            bf16x8 pb;
            if (ch2 == 0) {
#pragma unroll
                for (int j = 0; j < 8; j++)
                    pb[j] = bf16r(b2f(xng[el[et]][ib + j]) * f1[et]);
            } else {
#pragma unroll
                for (int j = 0; j < 8; j++)
                    pb[j] = (ib + j < 16) ? (short)innr[el[et]][ib + j] : (short)0;
            }
            bf16x8 ba = *(const bf16x8*)(biasf + (ch2 * 1024 + h * 512) + lane * 8);
            msgS[et] = __builtin_amdgcn_mfma_f32_16x16x32_bf16(ba, pb, zf, 0, 0, 0);
        }
        auto computeS = [&](int n, bf16x8 (&A)[4]) {
            f32x4 acc[4];
#pragma unroll
            for (int et = 0; et < 4; et++) acc[et] = zf;
#pragma unroll
            for (int kk = 0; kk < 4; kk++)
#pragma unroll
                for (int et = 0; et < 4; et++)
                    acc[et] = __builtin_amdgcn_mfma_f32_16x16x32_bf16(
                        A[kk], hfr[et][kk], acc[et], 0, 0, 0);
            float p[4];
            if (n < 32) {
#pragma unroll
                for (int et = 0; et < 4; et++) p[et] = f1[et] * b2f(xng[el[et]][n]);
            } else {
#pragma unroll
                for (int et = 0; et < 4; et++) p[et] = b2f(innr[el[et]][n - 32]);
            }
#pragma unroll
            for (int et = 0; et < 4; et++)
#pragma unroll
                for (int r = 0; r < 4; r++)
                    msgS[et][r] += p[et] * acc[et][r];
        };
        // 2-deep register prefetch, no barriers
        bf16x8 A0[4], A1[4];
        {
            const bf16x8* g = gp + nlo * 512 + h * 256;
#pragma unroll
            for (int f = 0; f < 4; f++) A0[f] = g[f * 64 + lane];
        }
        for (int n = nlo; n < nhi; n += 2) {
            const bf16x8* g1 = gp + (n + 1) * 512 + h * 256;
#pragma unroll
            for (int f = 0; f < 4; f++) A1[f] = g1[f * 64 + lane];
            computeS(n, A0);
            if (n + 2 < nhi) {
                const bf16x8* g2 = gp + (n + 2) * 512 + h * 256;
#pragma unroll
                for (int f = 0; f < 4; f++) A0[f] = g2[f * 64 + lane];
            }
            computeS(n + 1, A1);
        }
        // ---- epilogue: 16 channels (+den for s0), single-writer ----
        __syncthreads();
#pragma unroll
        for (int et = 0; et < 4; et++) {
            int le = el[et];
            float ew = ewl[le];
#pragma unroll
            for (int r = 0; r < 4; r++)
                msgl[le * 16 + q4 * 4 + r] = msgS[et][r] * ew;
        }
        __syncthreads();
        {
            int nch = (slice == 0) ? 17 : 16;
            int c = lane;
            int r0 = wid * 64;
            int rend = (cnt < r0 + 64) ? cnt : (r0 + 64);
            if (c < nch && r0 < cnt) {
                int cur = dstl[r0];
                float acc = 0.f;
                for (int r = r0; r < rend; r++) {
                    int nd = dstl[r];
                    if (nd != cur) {
                        if (cur >= 0) {
                            bool interior = (startp[cur] >= e0 + r0) && (startp[cur + 1] <= e0 + rend);
                            float* p = (c == 16) ? (den + cur)
                                     : ((slice == 0) ? (agg + cur * 80 + c)
                                     :  (slice == 1) ? (agg + cur * 80 + 16 + c)
                                     :  (slice == 2) ? (agg2 + cur * 32 + c)
                                                     : (agg2 + cur * 32 + 16 + c));
                            if (interior) *p = acc; else atomicAdd(p, acc);
                        }
                        acc = 0.f; cur = nd;
                    }
                    acc += (c == 16) ? ewl[r] : msgl[r * 16 + c];
                }
                if (cur >= 0) {
                    bool interior = (startp[cur] >= e0 + r0) && (startp[cur + 1] <= e0 + rend);
                    float* p = (c == 16) ? (den + cur)
                             : ((slice == 0) ? (agg + cur * 80 + c)
                             :  (slice == 1) ? (agg + cur * 80 + 16 + c)
                             :  (slice == 2) ? (agg2 + cur * 32 + c)
                                             : (agg2 + cur * 32 + 16 + c));
                    if (interior) *p = acc; else atomicAdd(p, acc);
                }
            }
        }
    } else {
        // ============ V slice: q3 phase [48,64) then qv phase [64,72) ===========
        float f4e[4];
#pragma unroll
        for (int et = 0; et < 4; et++) f4e[et] = A4C * sh0l[el[et]];
        // --- phase 1: q3 (w3), bias ba3 ---
        f32x4 q3[4];
#pragma unroll
        for (int et = 0; et < 4; et++) {
            bf16x8 xs8;
#pragma unroll
            for (int j = 0; j < 8; j++) xs8[j] = (short)xng[el[et]][ib + j];
            bf16x8 ba3 = *(const bf16x8*)(biasf + 2048 + lane * 8);
            q3[et] = __builtin_amdgcn_mfma_f32_16x16x32_bf16(ba3, xs8, zf, 0, 0, 0);
        }
        for (int n = 48; n < 64; ++n) {
            bf16x8 A[8];
            const bf16x8* g = gp + n * 512;
#pragma unroll
            for (int f = 0; f < 8; f++) A[f] = g[f * 64 + lane];
#pragma unroll
            for (int half = 0; half < 2; half++) {
                f32x4 acc[4];
#pragma unroll
                for (int et = 0; et < 4; et++) acc[et] = zf;
#pragma unroll
                for (int kk = 0; kk < 4; kk++)
#pragma unroll
                    for (int et = 0; et < 4; et++)
                        acc[et] = __builtin_amdgcn_mfma_f32_16x16x32_bf16(
                            A[half * 4 + kk], hfr[et][kk], acc[et], 0, 0, 0);
                int i = 2 * (n - 48) + half;
                float p[4];
#pragma unroll
                for (int et = 0; et < 4; et++) p[et] = b2f(xng[el[et]][i]);
#pragma unroll
                for (int et = 0; et < 4; et++)
#pragma unroll
                    for (int r = 0; r < 4; r++)
                        q3[et][r] += p[et] * acc[et][r];
            }
        }
        // --- phase 2: qv (w4), bias ba4 ---
        f32x4 qv[3][4];
#pragma unroll
        for (int et = 0; et < 4; et++) {
            bf16x8 ba4 = *(const bf16x8*)(biasf + 2560 + lane * 8);
#pragma unroll
            for (int m = 0; m < 3; m++) {
                bf16x8 t8;
#pragma unroll
                for (int j = 0; j < 8; j++) {
                    int i = ib + j;
                    t8[j] = (i < 16) ? (short)xng[el[et]][32 + 3 * i + m] : (short)0;
                }
                qv[m][et] = __builtin_amdgcn_mfma_f32_16x16x32_bf16(ba4, t8, zf, 0, 0, 0);
            }
        }
        for (int n = 64; n < 72; ++n) {
            bf16x8 A[8];
            const bf16x8* g = gp + n * 512;
#pragma unroll
            for (int f = 0; f < 8; f++) A[f] = g[f * 64 + lane];
#pragma unroll
            for (int half = 0; half < 2; half++) {
                f32x4 acc[4];
#pragma unroll
                for (int et = 0; et < 4; et++) acc[et] = zf;
#pragma unroll
                for (int kk = 0; kk < 4; kk++)
#pragma unroll
                    for (int et = 0; et < 4; et++)
                        acc[et] = __builtin_amdgcn_mfma_f32_16x16x32_bf16(
                            A[half * 4 + kk], hfr[et][kk], acc[et], 0, 0, 0);
                int i = 2 * (n - 64) + half;
#pragma unroll
                for (int m = 0; m < 3; m++) {
                    float p[4];
#pragma unroll
                    for (int et = 0; et < 4; et++) p[et] = b2f(xng[el[et]][32 + 3 * i + m]);
#pragma unroll
                    for (int et = 0; et < 4; et++)
#pragma unroll
                        for (int r = 0; r < 4; r++)
                            qv[m][et][r] += p[et] * acc[et][r];
                }
            }
        }
        // ---- epilogue: 48 V channels, single-writer ----
        __syncthreads();
#pragma unroll
        for (int et = 0; et < 4; et++) {
            int le = el[et];
            float ew = ewl[le];
            float s0 = sh1l[le][0], s1 = sh1l[le][1], s2 = sh1l[le][2];
            float b4 = f4e[et];
#pragma unroll
            for (int r = 0; r < 4; r++) {
                int o = q4 * 4 + r;
                float qq = A3C * q3[et][r];
                msgl[le * 48 + o * 3 + 0] = (qq * s0 + b4 * qv[0][et][r]) * ew;
                msgl[le * 48 + o * 3 + 1] = (qq * s1 + b4 * qv[1][et][r]) * ew;
                msgl[le * 48 + o * 3 + 2] = (qq * s2 + b4 * qv[2][et][r]) * ew;
            }
        }
        __syncthreads();
        {
            int c = lane;
            int r0 = wid * 64;
            int rend = (cnt < r0 + 64) ? cnt : (r0 + 64);
            if (c < 48 && r0 < cnt) {
                int cur = dstl[r0];
                float acc = 0.f;
                for (int r = r0; r < rend; r++) {
                    int nd = dstl[r];
                    if (nd != cur) {
                        if (cur >= 0) {
                            bool interior = (startp[cur] >= e0 + r0) && (startp[cur + 1] <= e0 + rend);
                            float* p = agg + cur * 80 + 32 + c;
                            if (interior) *p = acc; else atomicAdd(p, acc);
                        }
                        acc = 0.f; cur = nd;
                    }
                    acc += msgl[r * 48 + c];
                }
                if (cur >= 0) {
                    bool interior = (startp[cur] >= e0 + r0) && (startp[cur + 1] <= e0 + rend);
                    float* p = agg + cur * 80 + 32 + c;
                    if (interior) *p = acc; else atomicAdd(p, acc);
                }
            }
        }
    }
}

// ---------------- K_update: per-node update, 4 nodes/block ----------------------
__global__ __launch_bounds__(256) void k_update(
    const float* __restrict__ x, const float* __restrict__ xn,
    const float* __restrict__ agg, const float* __restrict__ agg2,
    const float* __restrict__ den,
    const float* __restrict__ Ws, const float* __restrict__ Wv,
    const float* __restrict__ Us, const float* __restrict__ Uv,
    const float* __restrict__ Ss, const float* __restrict__ Sv,
    const float* __restrict__ rsp, float* __restrict__ out) {
    int sub = threadIdx.x >> 6, t = threadIdx.x & 63;
    int n = blockIdx.x * 4 + sub;
    __shared__ float ag[4][DD];
    __shared__ float xnl[4][DD];
    __shared__ float sg[4][NS];
    __shared__ float gt[4][NV];
    __shared__ float vg[4][48];
    float idv = 1.0f / fmaxf(den[n], 1e-8f);
    float base = agg[n * DD + t];
    if (t < 32) base += agg2[n * 32 + t];
    ag[sub][t] = base * idv;
    if (t < 16) ag[sub][64 + t] = agg[n * DD + 64 + t] * idv;
    xnl[sub][t] = xn[n * DD + t];
    if (t < 16) xnl[sub][64 + t] = xn[n * DD + 64 + t];
    __syncthreads();
    const float iqs = 0.17677669529663687f;
    const float iqv = 0.25f;
    if (t < 48) {
        float acc = 0.f;
#pragma unroll
        for (int i = 0; i < NS; i++) acc += ag[sub][i] * Ws[i * 48 + t];
        acc *= iqs;
        if (t < NS) sg[sub][t] = silu_f(acc);
        else gt[sub][t - NS] = sigm(acc);
    }
    __syncthreads();
    if (t < 48) {
        int o = t / 3, m = t - 3 * o;
        float acc = 0.f;
#pragma unroll
        for (int i = 0; i < NV; i++) acc += ag[sub][NS + 3 * i + m] * Wv[i * NV + o];
        vg[sub][t] = acc * iqv * gt[sub][o];
    }
    __syncthreads();
    float rs = rsp[0];
    if (t < NS) {
        float us = 0.f, ss = 0.f;
#pragma unroll
        for (int i = 0; i < NS; i++) { us += sg[sub][i] * Us[i * NS + t]; ss += xnl[sub][i] * Ss[i * NS + t]; }
        out[n * DD + t] = x[n * DD + t] + rs * ((ss + us) * iqs);
    }
    if (t < 48) {
        int o = t / 3, m = t - 3 * o;
        float uv = 0.f, sv = 0.f;
#pragma unroll
        for (int i = 0; i < NV; i++) { uv += vg[sub][3 * i + m] * Uv[i * NV + o]; sv += xnl[sub][NS + 3 * i + m] * Sv[i * NV + o]; }
        out[n * DD + NS + t] = x[n * DD + NS + t] + rs * ((sv + uv) * iqv);
    }
}

extern "C" void kernel_launch(void* const* d_in, const int* in_sizes, int n_in,
                              void* d_out, int out_size, void* d_ws, size_t ws_size,
                              hipStream_t stream) {
    (void)in_sizes; (void)n_in; (void)out_size; (void)ws_size;
    const float* x    = (const float*)d_in[0];
    const int*   esrc = (const int*)d_in[1];
    const int*   edst = (const int*)d_in[2];
    const float* esh  = (const float*)d_in[3];
    const float* erbf = (const float*)d_in[4];
    const float* elen = (const float*)d_in[5];
    const float* nw   = (const float*)d_in[6];
    const float* nb   = (const float*)d_in[7];
    const float* mw1  = (const float*)d_in[8];
    const float* mb1  = (const float*)d_in[9];
    const float* mw2  = (const float*)d_in[10];
    const float* mb2  = (const float*)d_in[11];
    const float* mw3  = (const float*)d_in[12];
    const float* mb3  = (const float*)d_in[13];
    const float* gw1  = (const float*)d_in[14];
    const float* gb1  = (const float*)d_in[15];
    const float* gw2  = (const float*)d_in[16];
    const float* gb2  = (const float*)d_in[17];
    const float* Ws   = (const float*)d_in[18];
    const float* Wv   = (const float*)d_in[19];
    const float* Us   = (const float*)d_in[20];
    const float* Uv   = (const float*)d_in[21];
    const float* Ss   = (const float*)d_in[22];
    const float* Sv   = (const float*)d_in[23];
    const float* rsp  = (const float*)d_in[24];
    float* out = (float*)d_out;
    float* ws  = (float*)d_ws;

    // ws layout (float offsets); [0, 368000) zeroed in ONE memset:
    //   agg[0,256000) den[256000,259200) agg2[259200,361600)
    //   hist[361600,364800) cur[364800,368000)
    float* agg    = ws;
    float* den    = ws + 256000;
    float* agg2   = ws + 259200;
    int*   hist   = (int*)(ws + 361600);
    int*   cur    = (int*)(ws + 364800);
    int*   startp = (int*)(ws + 368000);       // 3201
    int*   inv    = (int*)(ws + 371204);       // 50000
    float* xn     = ws + 421204;               // 256000
    float* ewg    = ws + 677204;               // 50000 (perm-ordered)
    unsigned short* h2p = (unsigned short*)(ws + 727204);     // 6406144 bf16 (tiled)
    __hip_bfloat16* mw3f  = (__hip_bfloat16*)(ws + 3930276);  // 294912 bf16
    __hip_bfloat16* biasf = (__hip_bfloat16*)(ws + 4077732);  // 3072 bf16
    __hip_bfloat16* mw2f  = (__hip_bfloat16*)(ws + 4079268);  // 16384 bf16
    int* edstp    = (int*)(ws + 4087460);      // 50048
    int* esrcp    = (int*)(ws + 4137508);      // 50048
    float* eshp   = ws + 4187556;              // 200192 ([50048][4])
    unsigned short* xnb = (unsigned short*)(ws + 4387748);    // 256000 bf16
    // total: 4,515,748 floats ~= 18.1 MB

    hipMemsetAsync(ws, 0, 368000 * sizeof(float), stream);    // agg+den+agg2+hist+cur
    k_hist<<<196, 256, 0, stream>>>(edst, hist);
    k_scan_prep<<<9, 256, 0, stream>>>(hist, startp, mw2, mw2f);
    k_scatter<<<196, 256, 0, stream>>>(edst, esrc, esh, startp, cur,
                                       inv, edstp, esrcp, eshp);
    k_front<<<1727, 256, 0, stream>>>(erbf, elen, inv, mw1, mb1, gw1, gb1, gw2, gb2,
                                      mb2, mw2f, mw3, mb3, x, nw, nb,
                                      ewg, h2p, mw3f, biasf, xn, xnb);
    k_msg<<<1960, 128, 0, stream>>>(xnb, h2p, ewg, edstp, esrcp, eshp,
                                    mw3f, biasf, startp, agg, agg2, den);
    k_update<<<800, 256, 0, stream>>>(x, xn, agg, agg2, den, Ws, Wv, Us, Uv, Ss, Sv, rsp, out);
}